// Round 14
// baseline (97.409 us; speedup 1.0000x reference)
//
#include <hip/hip_runtime.h>
#include <hip/hip_bf16.h>

#define NN 2048
#define DD 128

typedef __attribute__((ext_vector_type(4))) float f32x4;
typedef __attribute__((ext_vector_type(8))) short short8;

__device__ __forceinline__ unsigned short f2bf_bits(float f) {
  union { __hip_bfloat16 h; unsigned short s; } u;
  u.h = __float2bfloat16(f);
  return u.s;
}

__device__ __forceinline__ short8 cvt8(f32x4 a, f32x4 b) {
  short8 r;
  r[0] = (short)f2bf_bits(a[0]); r[1] = (short)f2bf_bits(a[1]);
  r[2] = (short)f2bf_bits(a[2]); r[3] = (short)f2bf_bits(a[3]);
  r[4] = (short)f2bf_bits(b[0]); r[5] = (short)f2bf_bits(b[1]);
  r[6] = (short)f2bf_bits(b[2]); r[7] = (short)f2bf_bits(b[3]);
  return r;
}

__device__ __forceinline__ void gld16(const void* src, void* lds) {
  __builtin_amdgcn_global_load_lds(
      (const __attribute__((address_space(1))) void*)src,
      (__attribute__((address_space(3))) void*)lds, 16, 0, 0);
}

// ---------- K1: dnorm = rsqrt(rowsum(adj)+1e-8) (proven, ~21 µs) ----------
__global__ void k_degree(const float* __restrict__ adj, float* __restrict__ dnorm) {
  const int wv = threadIdx.x >> 6;
  const int ln = threadIdx.x & 63;
  const int row = blockIdx.x * 4 + wv;
  const f32x4* rowp = (const f32x4*)(adj + (size_t)row * NN);
  float s = 0.0f;
#pragma unroll
  for (int i = 0; i < 8; ++i) {
    f32x4 v = rowp[i * 64 + ln];
    s += v[0] + v[1] + v[2] + v[3];
  }
#pragma unroll
  for (int off = 32; off >= 1; off >>= 1) s += __shfl_xor(s, off);
  if (ln == 0) dnorm[row] = rsqrtf(s + 1e-8f);
}

// ---------- K2: yT[b][d][n] = bf16(dnorm[n] * (x@W)[n][d]) (proven) ----------
__global__ void k_y(const float* __restrict__ x, const float* __restrict__ W,
                    const float* __restrict__ dnorm, short* __restrict__ yT) {
  const int ln = threadIdx.x & 63;
  const int wv = threadIdx.x >> 6;
  const int bb = blockIdx.x >> 5;
  const int n0 = (blockIdx.x & 31) << 6;
  const int l15 = ln & 15, l4 = ln >> 4;
  const int dbase = wv * 32;

  short8 af[2][4];
#pragma unroll
  for (int dt = 0; dt < 2; ++dt)
#pragma unroll
    for (int ks = 0; ks < 4; ++ks) {
      short8 a;
#pragma unroll
      for (int j = 0; j < 8; ++j)
        a[j] = (short)f2bf_bits(W[(size_t)(ks * 32 + l4 * 8 + j) * DD + dbase + dt * 16 + l15]);
      af[dt][ks] = a;
    }

  f32x4 acc[2][4];
#pragma unroll
  for (int dt = 0; dt < 2; ++dt)
#pragma unroll
    for (int nt = 0; nt < 4; ++nt) acc[dt][nt] = (f32x4)0.0f;

  const float* xb = x + (size_t)bb * NN * DD;
  const float* dnb = dnorm + (size_t)bb * NN;
#pragma unroll
  for (int nt = 0; nt < 4; ++nt) {
    const int n = n0 + nt * 16 + l15;
    const float dn = dnb[n];
#pragma unroll
    for (int ks = 0; ks < 4; ++ks) {
      f32x4 p = *(const f32x4*)(xb + (size_t)n * DD + ks * 32 + l4 * 8);
      f32x4 q = *(const f32x4*)(xb + (size_t)n * DD + ks * 32 + l4 * 8 + 4);
      short8 bf = cvt8(p * dn, q * dn);
#pragma unroll
      for (int dt = 0; dt < 2; ++dt)
        acc[dt][nt] = __builtin_amdgcn_mfma_f32_16x16x32_bf16(af[dt][ks], bf, acc[dt][nt], 0, 0, 0);
    }
  }

  short* yb = yT + (size_t)bb * DD * NN;
#pragma unroll
  for (int dt = 0; dt < 2; ++dt)
#pragma unroll
    for (int nt = 0; nt < 4; ++nt)
#pragma unroll
      for (int rr = 0; rr < 4; ++rr) {
        int d = dbase + dt * 16 + l4 * 4 + rr;
        yb[(size_t)d * NN + n0 + nt * 16 + l15] = (short)f2bf_bits(acc[dt][nt][rr]);
      }
}

// ---------- K3: barrier-free wave-private GEMM ----------
// 256 blocks x 256 thr = 1024 waves; wave owns 16 rows x ALL 128 d.
// A: wave-private 4-buf LDS ring (4 KB tiles), staged 2 ahead via gld16
//    (pre-swizzled f32 source, linear dest, swizzled ds_read; cvt in reg).
// B: 16 x short8/iter from XCD-local L2 yT, depth-1, issued BEFORE stage so
//    the compiler's register-B vmcnt (24) preserves A-lead 2.
// Sync: s_waitcnt vmcnt(40) per iter (= 2 iters x [16B+4A] younger than A(t));
//    one vmcnt(0) after prologue; NO s_barrier anywhere (fixes the barrier
//    convoy that capped every prior GEMM at ~3 TB/s; r9's WAR flaw fixed by
//    LDS landing zone, r9's double-read fixed by full-d ownership).
__launch_bounds__(256)
__global__ void k_wgemm3(const float* __restrict__ adj, const short* __restrict__ yT,
                         const float* __restrict__ dnorm, const float* __restrict__ bias,
                         float* __restrict__ out) {
  __shared__ char As[4][4][4096];  // [wave][buf][16 rows x 64 k f32]

  const int t = threadIdx.x;
  const int ln = t & 63;
  const int wv = t >> 6;
  const int l15 = ln & 15, l4 = ln >> 4;
  // XCD-bijective swizzle: XCD x owns batch x (yT slice stays in its L2)
  const int orig = ((blockIdx.x & 7) << 5) | (blockIdx.x >> 3);
  const int bb = orig >> 5;
  const size_t rowbase = (size_t)bb * NN + ((size_t)(orig & 31) << 6) + (wv << 4);

  const char* awave = (const char*)(adj + rowbase * NN);
  char* ldsb = &As[wv][0][0];

  const short* ybb = yT + (size_t)bb * DD * NN + (l4 << 3);
  const short* bp[8];
#pragma unroll
  for (int c = 0; c < 8; ++c) bp[c] = ybb + (size_t)(c * 16 + l15) * NN;

  f32x4 acc[8];
#pragma unroll
  for (int c = 0; c < 8; ++c) acc[c] = (f32x4)0.f;

  auto stage = [&](int kt, int buf) {
#pragma unroll
    for (int j = 0; j < 4; ++j) {
      unsigned L = ((unsigned)j << 10) + ((unsigned)ln << 4);
      unsigned row = L >> 8;
      unsigned off = L & 255u;
      unsigned soff = off ^ ((row & 7u) << 4);
      gld16(awave + (size_t)row * (NN * 4) + (size_t)kt * 256 + soff,
            ldsb + (buf << 12) + L);
    }
  };
  auto compute = [&](int buf, short8 B0[8], short8 B1[8]) {
    const char* base = ldsb + (buf << 12);
    const unsigned sw = ((unsigned)l15 & 7u) << 4;
    const unsigned rowb = (unsigned)l15 << 8;
#pragma unroll
    for (int ks = 0; ks < 2; ++ks) {
      unsigned o = (unsigned)(ks * 128 + l4 * 32);
      f32x4 f0 = *(const f32x4*)(base + rowb + (o ^ sw));
      f32x4 f1 = *(const f32x4*)(base + rowb + ((o + 16) ^ sw));
      short8 af = cvt8(f0, f1);
#pragma unroll
      for (int c = 0; c < 8; ++c)
        acc[c] = __builtin_amdgcn_mfma_f32_16x16x32_bf16(af, ks ? B1[c] : B0[c], acc[c], 0, 0, 0);
    }
  };

  // prologue: B(0) -> E set, A tiles 0,1 staged, one-time full drain (no barrier)
  short8 E0[8], E1[8], O0[8], O1[8];
#pragma unroll
  for (int c = 0; c < 8; ++c) {
    E0[c] = *(const short8*)(bp[c]);
    E1[c] = *(const short8*)(bp[c] + 32);
  }
  stage(0, 0);
  stage(1, 1);
  asm volatile("s_waitcnt vmcnt(0)" ::: "memory");

#pragma unroll 1
  for (int t2 = 0; t2 < 32; t2 += 2) {
    // even iter t2: load B(t2+1)->O, stage A(t2+2), wait A(t2), compute with E
    {
      const int bt = (t2 + 1) & 31;
#pragma unroll
      for (int c = 0; c < 8; ++c) {
        O0[c] = *(const short8*)(bp[c] + bt * 64);
        O1[c] = *(const short8*)(bp[c] + bt * 64 + 32);
      }
      stage((t2 + 2) & 31, (t2 + 2) & 3);
      asm volatile("s_waitcnt vmcnt(40)" ::: "memory");
      compute(t2 & 3, E0, E1);
    }
    // odd iter t2+1: load B(t2+2)->E, stage A(t2+3), wait A(t2+1), compute with O
    {
      const int bt = (t2 + 2) & 31;
#pragma unroll
      for (int c = 0; c < 8; ++c) {
        E0[c] = *(const short8*)(bp[c] + bt * 64);
        E1[c] = *(const short8*)(bp[c] + bt * 64 + 32);
      }
      stage((t2 + 3) & 31, (t2 + 3) & 3);
      asm volatile("s_waitcnt vmcnt(40)" ::: "memory");
      compute((t2 + 1) & 3, O0, O1);
    }
  }

  // epilogue: out = dnorm_row * acc + bias
  f32x4 dn4 = *(const f32x4*)(dnorm + rowbase + (l4 << 2));
#pragma unroll
  for (int c = 0; c < 8; ++c) {
    const float bv = bias[c * 16 + l15];
#pragma unroll
    for (int rr = 0; rr < 4; ++rr)
      out[(rowbase + (l4 << 2) + rr) * DD + c * 16 + l15] = acc[c][rr] * dn4[rr] + bv;
  }
}

extern "C" void kernel_launch(void* const* d_in, const int* in_sizes, int n_in,
                              void* d_out, int out_size, void* d_ws, size_t ws_size,
                              hipStream_t stream) {
  (void)in_sizes; (void)n_in; (void)out_size; (void)ws_size;
  const float* x = (const float*)d_in[0];
  const float* adj = (const float*)d_in[1];
  const float* W = (const float*)d_in[2];
  const float* bias = (const float*)d_in[3];
  float* out = (float*)d_out;

  char* ws = (char*)d_ws;
  float* dnorm = (float*)ws;             // 64 KB
  short* yT = (short*)(ws + (1 << 16));  // 4 MB

  k_degree<<<4096, 256, 0, stream>>>(adj, dnorm);
  k_y<<<256, 256, 0, stream>>>(x, W, dnorm, yT);
  k_wgemm3<<<256, 256, 0, stream>>>(adj, yT, dnorm, bias, out);
}

// Round 15
// 67.318 us; speedup vs baseline: 1.4470x; 1.4470x over previous
//
#include <hip/hip_runtime.h>
#include <hip/hip_bf16.h>

#define NN 2048
#define DD 128

typedef __attribute__((ext_vector_type(4))) float f32x4;
typedef __attribute__((ext_vector_type(8))) short short8;

__device__ __forceinline__ unsigned short f2bf_bits(float f) {
  union { __hip_bfloat16 h; unsigned short s; } u;
  u.h = __float2bfloat16(f);
  return u.s;
}

__device__ __forceinline__ short8 cvt8(f32x4 a, f32x4 b) {
  short8 r;
  r[0] = (short)f2bf_bits(a[0]); r[1] = (short)f2bf_bits(a[1]);
  r[2] = (short)f2bf_bits(a[2]); r[3] = (short)f2bf_bits(a[3]);
  r[4] = (short)f2bf_bits(b[0]); r[5] = (short)f2bf_bits(b[1]);
  r[6] = (short)f2bf_bits(b[2]); r[7] = (short)f2bf_bits(b[3]);
  return r;
}

__device__ __forceinline__ void gld16(const void* src, void* lds) {
  __builtin_amdgcn_global_load_lds(
      (const __attribute__((address_space(1))) void*)src,
      (__attribute__((address_space(3))) void*)lds, 16, 0, 0);
}

// ---------- K1: dnorm = rsqrt(rowsum(adj)+1e-8) (proven, ~21 µs) ----------
__global__ void k_degree(const float* __restrict__ adj, float* __restrict__ dnorm) {
  const int wv = threadIdx.x >> 6;
  const int ln = threadIdx.x & 63;
  const int row = blockIdx.x * 4 + wv;
  const f32x4* rowp = (const f32x4*)(adj + (size_t)row * NN);
  float s = 0.0f;
#pragma unroll
  for (int i = 0; i < 8; ++i) {
    f32x4 v = rowp[i * 64 + ln];
    s += v[0] + v[1] + v[2] + v[3];
  }
#pragma unroll
  for (int off = 32; off >= 1; off >>= 1) s += __shfl_xor(s, off);
  if (ln == 0) dnorm[row] = rsqrtf(s + 1e-8f);
}

// ---------- K2: yT[b][d][n] = bf16(dnorm[n] * (x@W)[n][d]) (proven) ----------
__global__ void k_y(const float* __restrict__ x, const float* __restrict__ W,
                    const float* __restrict__ dnorm, short* __restrict__ yT) {
  const int ln = threadIdx.x & 63;
  const int wv = threadIdx.x >> 6;
  const int bb = blockIdx.x >> 5;
  const int n0 = (blockIdx.x & 31) << 6;
  const int l15 = ln & 15, l4 = ln >> 4;
  const int dbase = wv * 32;

  short8 af[2][4];
#pragma unroll
  for (int dt = 0; dt < 2; ++dt)
#pragma unroll
    for (int ks = 0; ks < 4; ++ks) {
      short8 a;
#pragma unroll
      for (int j = 0; j < 8; ++j)
        a[j] = (short)f2bf_bits(W[(size_t)(ks * 32 + l4 * 8 + j) * DD + dbase + dt * 16 + l15]);
      af[dt][ks] = a;
    }

  f32x4 acc[2][4];
#pragma unroll
  for (int dt = 0; dt < 2; ++dt)
#pragma unroll
    for (int nt = 0; nt < 4; ++nt) acc[dt][nt] = (f32x4)0.0f;

  const float* xb = x + (size_t)bb * NN * DD;
  const float* dnb = dnorm + (size_t)bb * NN;
#pragma unroll
  for (int nt = 0; nt < 4; ++nt) {
    const int n = n0 + nt * 16 + l15;
    const float dn = dnb[n];
#pragma unroll
    for (int ks = 0; ks < 4; ++ks) {
      f32x4 p = *(const f32x4*)(xb + (size_t)n * DD + ks * 32 + l4 * 8);
      f32x4 q = *(const f32x4*)(xb + (size_t)n * DD + ks * 32 + l4 * 8 + 4);
      short8 bf = cvt8(p * dn, q * dn);
#pragma unroll
      for (int dt = 0; dt < 2; ++dt)
        acc[dt][nt] = __builtin_amdgcn_mfma_f32_16x16x32_bf16(af[dt][ks], bf, acc[dt][nt], 0, 0, 0);
    }
  }

  short* yb = yT + (size_t)bb * DD * NN;
#pragma unroll
  for (int dt = 0; dt < 2; ++dt)
#pragma unroll
    for (int nt = 0; nt < 4; ++nt)
#pragma unroll
      for (int rr = 0; rr < 4; ++rr) {
        int d = dbase + dt * 16 + l4 * 4 + rr;
        yb[(size_t)d * NN + n0 + nt * 16 + l15] = (short)f2bf_bits(acc[dt][nt][rr]);
      }
}

// ---------- K3: out = dnorm_row * (adj @ y) + b — super-tile staging ----------
// THE fix isolated from 14 rounds: every prior GEMM staged A in 128-256 B
// HBM segments (2.2-3.2 TB/s); every row-contiguous >=1KB kernel hits
// 5.6-6.4 TB/s. Here each gld16 covers ONE ROW's 1 KB contiguously
// (BK=256 super-tile, 64 rows, wave w stages rows w*8..w*8+8). LDS
// [64 rows][1 KB], source+read 16B-unit XOR swizzle u^=(row&7) (closed
// within each row's 128 B group; frag reads 2-way bank = free). 8 barriers
// total (1 per super-tile); B a full super-tile ahead in E/O reg sets;
// end-of-iter s_waitcnt vmcnt(8) keeps only B(S+1) outstanding.
__launch_bounds__(512, 1)
__global__ void k_gemm4(const float* __restrict__ adj, const short* __restrict__ yT,
                        const float* __restrict__ dnorm, const float* __restrict__ bias,
                        float* __restrict__ out) {
  __shared__ char As[2][65536];  // 2 x 64 KB: [64 rows][256 k f32 = 1 KB]

  const int t = threadIdx.x;
  const int ln = t & 63;
  const int wv = t >> 6;
  const int l15 = ln & 15, l4 = ln >> 4;
  const int orig = ((blockIdx.x & 7) << 5) | (blockIdx.x >> 3);  // XCD-bijective
  const int bb = orig >> 5;
  const int m0 = (orig & 31) << 6;

  const char* ablk = (const char*)(adj + ((size_t)bb * NN + m0) * NN);
  const int oc = (wv << 4) + l15;
  const int kg8 = l4 << 3;
  const short* ybase = yT + ((size_t)bb * DD + oc) * NN;

  f32x4 acc[4];
#pragma unroll
  for (int m = 0; m < 4; ++m) acc[m] = (f32x4)0.0f;

  // stage super-tile S into buf: wave w stages rows w*8+i, i=0..7, each as
  // ONE contiguous 1 KB wave read (lane ln -> source unit ln^(i&7), dest
  // linear) — identical HBM access shape to k_degree.
  auto stage = [&](int S, int buf) {
#pragma unroll
    for (int i = 0; i < 8; ++i) {
      const int row = (wv << 3) + i;
      const char* src = ablk + (size_t)row * (NN * 4) + (size_t)S * 1024 +
                        (((unsigned)(ln ^ (i & 7))) << 4);
      gld16(src, (char*)As + (buf << 16) + ((unsigned)row << 10));
    }
  };
  // B fragments for super-tile S: 8 short8 (one per 32-k step)
  auto loadB = [&](int S, short8 B[8]) {
#pragma unroll
    for (int kk = 0; kk < 8; ++kk)
      B[kk] = *(const short8*)(ybase + S * 256 + kk * 32 + kg8);
  };
  auto compute = [&](int buf, short8 B[8]) {
    const char* base = (const char*)As + (buf << 16);
#pragma unroll
    for (int kk = 0; kk < 8; ++kk) {
#pragma unroll
      for (int m = 0; m < 4; ++m) {
        const unsigned row = (unsigned)(m * 16 + l15);
        const unsigned s = row & 7u;
        const unsigned q0 = (unsigned)(kk * 8 + l4 * 2);
        f32x4 f0 = *(const f32x4*)(base + (row << 10) + ((q0 ^ s) << 4));
        f32x4 f1 = *(const f32x4*)(base + (row << 10) + (((q0 + 1) ^ s) << 4));
        acc[m] = __builtin_amdgcn_mfma_f32_16x16x32_bf16(cvt8(f0, f1), B[kk], acc[m], 0, 0, 0);
      }
    }
  };

  short8 E[8], O[8];
  // prologue: stage(0), B(0), full drain, barrier
  stage(0, 0);
  loadB(0, E);
  asm volatile("s_waitcnt vmcnt(0)\n\ts_barrier" ::: "memory");

#pragma unroll 1
  for (int S2 = 0; S2 < 8; S2 += 2) {
    // even super-tile S2: prefetch S2+1, compute S2 (E), sync
    if (S2 + 1 < 8) { stage(S2 + 1, (S2 + 1) & 1); loadB(S2 + 1, O); }
    compute(S2 & 1, E);
    if (S2 + 1 < 8)
      asm volatile("s_waitcnt vmcnt(8)\n\ts_barrier" ::: "memory");
    // odd super-tile S2+1: prefetch S2+2, compute S2+1 (O), sync
    if (S2 + 1 < 8) {
      if (S2 + 2 < 8) { stage(S2 + 2, (S2 + 2) & 1); loadB(S2 + 2, E); }
      compute((S2 + 1) & 1, O);
      if (S2 + 2 < 8)
        asm volatile("s_waitcnt vmcnt(8)\n\ts_barrier" ::: "memory");
    }
  }

  // epilogue: out = dnorm_row * acc + bias (r12-verbatim)
  const float bv = bias[oc];
  const int rbase = l4 << 2;
#pragma unroll
  for (int m = 0; m < 4; ++m) {
    f32x4 dn = *(const f32x4*)(dnorm + (size_t)bb * NN + m0 + m * 16 + rbase);
#pragma unroll
    for (int rr = 0; rr < 4; ++rr)
      out[(size_t)(bb * NN + m0 + m * 16 + rbase + rr) * DD + oc] = acc[m][rr] * dn[rr] + bv;
  }
}

extern "C" void kernel_launch(void* const* d_in, const int* in_sizes, int n_in,
                              void* d_out, int out_size, void* d_ws, size_t ws_size,
                              hipStream_t stream) {
  (void)in_sizes; (void)n_in; (void)out_size; (void)ws_size;
  const float* x = (const float*)d_in[0];
  const float* adj = (const float*)d_in[1];
  const float* W = (const float*)d_in[2];
  const float* bias = (const float*)d_in[3];
  float* out = (float*)d_out;

  char* ws = (char*)d_ws;
  float* dnorm = (float*)ws;             // 64 KB
  short* yT = (short*)(ws + (1 << 16));  // 4 MB

  k_degree<<<4096, 256, 0, stream>>>(adj, dnorm);
  k_y<<<256, 256, 0, stream>>>(x, W, dnorm, yT);
  k_gemm4<<<256, 512, 0, stream>>>(adj, yT, dnorm, bias, out);
}